// Round 1
// baseline (463.122 us; speedup 1.0000x reference)
//
#include <hip/hip_runtime.h>
#include <cstdint>
#include <cstddef>

// Problem constants (reference: B=4, N=2048, DIM=256, heads=8, groups=2)
#define B_    4
#define NPT   2048
#define DIM_  256
#define QKVW  768   // 3*DIM

__device__ __forceinline__ float gelu_f(float x) {
  // exact gelu: x * 0.5 * (1 + erf(x/sqrt(2)))
  return 0.5f * x * (1.0f + erff(x * 0.70710678118654752440f));
}

// ---------------------------------------------------------------------------
// KNN: per (b,n) find 32 nearest (squared dist, stable by index). Block=256,
// 8 candidates/thread held in registers as key=(dist_bits<<32)|j; 32 rounds of
// global min-extraction (wave shfl reduce + LDS across 4 waves).
// ---------------------------------------------------------------------------
__global__ __launch_bounds__(256) void knn_kernel(const float* __restrict__ pos,
                                                  int* __restrict__ idx_out) {
  int bn = blockIdx.x;
  int b = bn >> 11, n = bn & (NPT - 1);
  const float* pb = pos + (size_t)b * NPT * 3;
  float qx = pb[n * 3 + 0], qy = pb[n * 3 + 1], qz = pb[n * 3 + 2];
  int t = threadIdx.x;
  unsigned long long keys[8];
  {
    // Match numpy rounding: no FMA contraction, left-to-right adds.
#pragma clang fp contract(off)
#pragma unroll
    for (int s = 0; s < 8; s++) {
      int j = t + (s << 8);
      float dx = qx - pb[j * 3 + 0];
      float dy = qy - pb[j * 3 + 1];
      float dz = qz - pb[j * 3 + 2];
      float d = dx * dx;
      d = d + dy * dy;
      d = d + dz * dz;
      // d >= 0 so IEEE bits are monotonic as uint; index in low bits = stable ties
      keys[s] = ((unsigned long long)__float_as_uint(d) << 32) | (unsigned int)j;
    }
  }
  __shared__ unsigned long long wmin[4];
  __shared__ unsigned long long gminS;
  int lane = t & 63, wid = t >> 6;
  for (int it = 0; it < 32; it++) {
    unsigned long long k = keys[0];
#pragma unroll
    for (int s = 1; s < 8; s++) k = (keys[s] < k) ? keys[s] : k;
#pragma unroll
    for (int off = 32; off > 0; off >>= 1) {
      unsigned long long o = __shfl_down(k, off, 64);
      if (o < k) k = o;
    }
    if (lane == 0) wmin[wid] = k;
    __syncthreads();
    if (t == 0) {
      unsigned long long gm = wmin[0];
      for (int w = 1; w < 4; w++) gm = (wmin[w] < gm) ? wmin[w] : gm;
      gminS = gm;
      idx_out[(size_t)bn * 32 + it] = (int)(unsigned int)(gm & 0xffffffffULL);
    }
    __syncthreads();
    unsigned long long g = gminS;
#pragma unroll
    for (int s = 0; s < 8; s++)
      if (keys[s] == g) keys[s] = ~0ULL;  // remove extracted key (unique by index)
  }
}

// ---------------------------------------------------------------------------
// fp32 tiled GEMM, 64x64 tile, K-tile 16, 256 threads, 4x4 per thread.
// MODE 0: C = A@B                      (qkv)
// MODE 1: C = gelu(A@B + bias)        (proj)
// MODE 2: C = extra + (A*av)@B + bias (head; av indexed [batch*256+k], N==256)
// ---------------------------------------------------------------------------
template <int MODE>
__global__ __launch_bounds__(256) void gemm64(const float* __restrict__ A,
                                              const float* __restrict__ Bm,
                                              const float* __restrict__ bias,
                                              const float* __restrict__ extra,
                                              const float* __restrict__ av,
                                              float* __restrict__ C,
                                              int M, int N, int K) {
  __shared__ float As[16][65];  // [k][m], +1 pad
  __shared__ float Bs[16][64];  // [k][n]
  int tid = threadIdx.x;
  int tx = tid & 15, ty = tid >> 4;
  int tileN = blockIdx.x * 64, tileM = blockIdx.y * 64;
  int arow = tid >> 2;           // 0..63
  int acol4 = (tid & 3) * 4;     // 0,4,8,12
  int brow = tid >> 4;           // 0..15
  int bcol4 = (tid & 15) * 4;
  int batch = (tileM + arow) >> 11;  // rows of a tile share the batch (64|2048)
  float acc[4][4] = {};
  for (int k0 = 0; k0 < K; k0 += 16) {
    float4 a = *(const float4*)(A + (size_t)(tileM + arow) * K + k0 + acol4);
    if (MODE == 2) {
      const float* avb = av + batch * 256 + k0 + acol4;
      a.x *= avb[0]; a.y *= avb[1]; a.z *= avb[2]; a.w *= avb[3];
    }
    float4 bv = *(const float4*)(Bm + (size_t)(k0 + brow) * N + tileN + bcol4);
    As[acol4 + 0][arow] = a.x;
    As[acol4 + 1][arow] = a.y;
    As[acol4 + 2][arow] = a.z;
    As[acol4 + 3][arow] = a.w;
    *(float4*)&Bs[brow][bcol4] = bv;
    __syncthreads();
#pragma unroll
    for (int kk = 0; kk < 16; kk++) {
      float ar[4], br[4];
#pragma unroll
      for (int i = 0; i < 4; i++) ar[i] = As[kk][ty + 16 * i];
#pragma unroll
      for (int j = 0; j < 4; j++) br[j] = Bs[kk][tx + 16 * j];
#pragma unroll
      for (int i = 0; i < 4; i++)
#pragma unroll
        for (int j = 0; j < 4; j++) acc[i][j] += ar[i] * br[j];
    }
    __syncthreads();
  }
#pragma unroll
  for (int i = 0; i < 4; i++) {
    int row = tileM + ty + 16 * i;
#pragma unroll
    for (int j = 0; j < 4; j++) {
      int col = tileN + tx + 16 * j;
      float v = acc[i][j];
      if (MODE == 1) v = gelu_f(v + bias[col]);
      else if (MODE == 2) v = extra[(size_t)row * 256 + col] + (v + bias[col]);
      C[(size_t)row * N + col] = v;
    }
  }
}

// ---------------------------------------------------------------------------
// Fused neighborhood attention, one block(128) per (b,n,group).
// rp[j][c] = gelu(rel@Wp + bp); attn_rel = per-head sum; logits = q.k*SCALE+ar;
// softmax over neighbors; out = sum a*(v+rp).
// ---------------------------------------------------------------------------
__global__ __launch_bounds__(128) void attn_kernel(
    const float* __restrict__ qkv, const float* __restrict__ pos,
    const int* __restrict__ knn,
    const float* __restrict__ Wp0, const float* __restrict__ bp0,
    const float* __restrict__ Wp1, const float* __restrict__ bp1,
    float* __restrict__ xcat) {
  const float SCALE = 0.17677669529663687f;  // 32^-0.5
  int g = blockIdx.y;
  int bn = blockIdx.x;
  int b = bn >> 11, n = bn & (NPT - 1);
  int nk = g ? 32 : 16;
  const float* Wp = g ? Wp1 : Wp0;
  const float* bp = g ? bp1 : bp0;
  int t = threadIdx.x;  // 0..127 = output channel within group
  __shared__ float q_s[128];
  __shared__ float rel_s[32][3];
  __shared__ int idx_s[32];
  __shared__ float rp[32][129];  // +1 pad: conflict-free per-head row sums
  __shared__ float logits[4][32];
  __shared__ float denom[4];
  const float* qkvb = qkv + (size_t)b * NPT * QKVW;
  q_s[t] = qkvb[(size_t)n * QKVW + g * 128 + t];
  if (t < nk) {
    int j = knn[(size_t)bn * 32 + t];
    idx_s[t] = j;
    rel_s[t][0] = pos[((size_t)b * NPT + n) * 3 + 0] - pos[((size_t)b * NPT + j) * 3 + 0];
    rel_s[t][1] = pos[((size_t)b * NPT + n) * 3 + 1] - pos[((size_t)b * NPT + j) * 3 + 1];
    rel_s[t][2] = pos[((size_t)b * NPT + n) * 3 + 2] - pos[((size_t)b * NPT + j) * 3 + 2];
  }
  __syncthreads();
  // rel-pos MLP
  float w0 = Wp[t], w1 = Wp[128 + t], w2 = Wp[256 + t], bb = bp[t];
  for (int j = 0; j < nk; j++) {
    float x = rel_s[j][0] * w0 + rel_s[j][1] * w1 + rel_s[j][2] * w2 + bb;
    rp[j][t] = gelu_f(x);
  }
  __syncthreads();
  // attn_rel + logits: thread -> (head h, neighbor j)
  {
    int h, j;
    bool active;
    if (nk == 32) { h = t >> 5; j = t & 31; active = true; }
    else          { h = t >> 4; j = t & 15; active = (t < 64); }
    if (active) {
      float ar = 0.f;
#pragma unroll
      for (int d = 0; d < 32; d++) ar += rp[j][h * 32 + d];
      const float* kr = qkvb + (size_t)idx_s[j] * QKVW + 256 + g * 128 + h * 32;
      float dot = 0.f;
#pragma unroll
      for (int d = 0; d < 32; d++) dot += q_s[h * 32 + d] * kr[d];
      logits[h][j] = dot * SCALE + ar;
    }
  }
  __syncthreads();
  // v' = rp + gathered v (in place; each thread touches only its own column)
  for (int j = 0; j < nk; j++)
    rp[j][t] += qkvb[(size_t)idx_s[j] * QKVW + 512 + g * 128 + t];
  // softmax numerator/denominator per head (4 threads, nk iters each)
  if (t < 4) {
    float mx = -3.4e38f;
    for (int j = 0; j < nk; j++) mx = fmaxf(mx, logits[t][j]);
    float s = 0.f;
    for (int j = 0; j < nk; j++) {
      float e = expf(logits[t][j] - mx);
      logits[t][j] = e;
      s += e;
    }
    denom[t] = s;
  }
  __syncthreads();
  int hh = t >> 5;
  float acc = 0.f;
  for (int j = 0; j < nk; j++) acc += logits[hh][j] * rp[j][t];
  acc /= denom[hh];
  xcat[((size_t)b * NPT + n) * DIM_ + g * 128 + t] = acc;
}

// ---------------------------------------------------------------------------
// Column partial sums of feats_proj (mean over N later). grid (B,32), 64 rows each.
// ---------------------------------------------------------------------------
__global__ __launch_bounds__(256) void colsum_kernel(const float* __restrict__ fp,
                                                     float* __restrict__ part) {
  int b = blockIdx.x, ch = blockIdx.y, t = threadIdx.x;
  const float* base = fp + ((size_t)(b * NPT + ch * 64)) * DIM_ + t;
  float s = 0.f;
  for (int r = 0; r < 64; r++) s += base[(size_t)r * DIM_];
  part[((size_t)b * 32 + ch) * DIM_ + t] = s;
}

// ---------------------------------------------------------------------------
// Tiny MSF MLP: S=mean -> Z=gelu(S@Wfc1+b) -> av=Z@Wfc2+b -> pairwise softmax.
// One block per batch, 256 threads.
// ---------------------------------------------------------------------------
__global__ __launch_bounds__(256) void msf_small_kernel(
    const float* __restrict__ part, const float* __restrict__ Wfc1,
    const float* __restrict__ bfc1, const float* __restrict__ Wfc2,
    const float* __restrict__ bfc2, float* __restrict__ av_out) {
  int b = blockIdx.x, t = threadIdx.x;
  __shared__ float S[256], Z[128], A[256];
  float s = 0.f;
  for (int ch = 0; ch < 32; ch++) s += part[((size_t)b * 32 + ch) * DIM_ + t];
  S[t] = s * (1.0f / 2048.0f);
  __syncthreads();
  if (t < 128) {
    float z = bfc1[t];
    for (int i = 0; i < 256; i++) z += S[i] * Wfc1[i * 128 + t];
    Z[t] = gelu_f(z);
  }
  __syncthreads();
  float a = bfc2[t];
  for (int j = 0; j < 128; j++) a += Z[j] * Wfc2[j * 256 + t];
  A[t] = a;
  __syncthreads();
  float pA = A[t ^ 128];  // softmax over the 2 groups, per channel
  float m = fmaxf(a, pA);
  float e = expf(a - m);
  av_out[(size_t)b * 256 + t] = e / (e + expf(pA - m));
}

// ---------------------------------------------------------------------------
extern "C" void kernel_launch(void* const* d_in, const int* in_sizes, int n_in,
                              void* d_out, int out_size, void* d_ws, size_t ws_size,
                              hipStream_t stream) {
  const float* x     = (const float*)d_in[0];
  const float* pos   = (const float*)d_in[1];
  const float* Wqkv  = (const float*)d_in[2];
  const float* Wp0   = (const float*)d_in[3];
  const float* bp0   = (const float*)d_in[4];
  const float* Wp1   = (const float*)d_in[5];
  const float* bp1   = (const float*)d_in[6];
  const float* Wproj = (const float*)d_in[7];
  const float* bproj = (const float*)d_in[8];
  const float* Wfc1  = (const float*)d_in[9];
  const float* bfc1  = (const float*)d_in[10];
  const float* Wfc2  = (const float*)d_in[11];
  const float* bfc2  = (const float*)d_in[12];
  const float* Whead = (const float*)d_in[13];
  const float* bhead = (const float*)d_in[14];
  float* out = (float*)d_out;

  // Workspace layout (bytes):
  //   [0, 1MB)            knn idx  [B*N][32] int
  //   [1MB, 1MB+25.2MB)   qkv      [B*N][768] f32  -- reused as feats_proj after attention
  //   [+, +8.4MB)         xcat     [B*N][256] f32
  //   [+, +128KB)         colsum partials [B][32][256] f32
  //   [+, +4KB)           av_sm    [B][256] f32
  char* ws = (char*)d_ws;
  size_t off = 0;
  int* idx = (int*)(ws + off);          off += (size_t)B_ * NPT * 32 * 4;      // 1 MiB
  float* qkv = (float*)(ws + off);      off += (size_t)B_ * NPT * QKVW * 4;    // 25.2 MB
  float* fp = qkv;  // reuse: qkv dead after attention
  float* xcat = (float*)(ws + off);     off += (size_t)B_ * NPT * DIM_ * 4;    // 8.4 MB
  float* part = (float*)(ws + off);     off += (size_t)B_ * 32 * DIM_ * 4;     // 128 KiB
  float* av = (float*)(ws + off);       off += (size_t)B_ * DIM_ * 4;          // 4 KiB

  const int M = B_ * NPT;  // 8192

  knn_kernel<<<M, 256, 0, stream>>>(pos, idx);
  gemm64<0><<<dim3(QKVW / 64, M / 64), 256, 0, stream>>>(
      x, Wqkv, nullptr, nullptr, nullptr, qkv, M, QKVW, DIM_);
  attn_kernel<<<dim3(M, 2), 128, 0, stream>>>(qkv, pos, idx, Wp0, bp0, Wp1, bp1, xcat);
  gemm64<1><<<dim3(DIM_ / 64, M / 64), 256, 0, stream>>>(
      xcat, Wproj, bproj, nullptr, nullptr, fp, M, DIM_, DIM_);
  colsum_kernel<<<dim3(B_, 32), 256, 0, stream>>>(fp, part);
  msf_small_kernel<<<B_, 256, 0, stream>>>(part, Wfc1, bfc1, Wfc2, bfc2, av);
  gemm64<2><<<dim3(DIM_ / 64, M / 64), 256, 0, stream>>>(
      xcat, Whead, bhead, fp, av, out, M, DIM_, DIM_);
}

// Round 2
// 437.270 us; speedup vs baseline: 1.0591x; 1.0591x over previous
//
#include <hip/hip_runtime.h>
#include <cstdint>
#include <cstddef>

// Problem constants (reference: B=4, N=2048, DIM=256, heads=8, groups=2)
#define B_    4
#define NPT   2048
#define DIM_  256
#define QKVW  768   // 3*DIM

__device__ __forceinline__ float gelu_f(float x) {
  // exact gelu: x * 0.5 * (1 + erf(x/sqrt(2)))
  return 0.5f * x * (1.0f + erff(x * 0.70710678118654752440f));
}

// ---------------------------------------------------------------------------
// KNN v2: ONE WAVE per query (4 queries / 256-thread block). No __syncthreads.
// Each lane holds 32 candidates as packed key = (dist_bits<<32)|idx (dist>=0 so
// IEEE bits are order-preserving; low-bits index = stable tie-break, matching
// numpy argsort). 2-level tournament per lane (4 group-mins of 8) so the
// extraction removal rescans only 8 keys, exec-masked to the single owner lane.
// 32 rounds of 6-level shfl_xor butterfly min across the wave.
// ---------------------------------------------------------------------------
__global__ __launch_bounds__(256) void knn_kernel(const float* __restrict__ pos,
                                                  int* __restrict__ idx_out) {
  int wq = blockIdx.x * 4 + (threadIdx.x >> 6);  // query id 0..8191
  int lane = threadIdx.x & 63;
  int b = wq >> 11, n = wq & (NPT - 1);
  const float* pb = pos + (size_t)b * NPT * 3;
  float qx = pb[n * 3 + 0], qy = pb[n * 3 + 1], qz = pb[n * 3 + 2];

  unsigned long long keys[32];
  {
    // Match numpy rounding: no FMA contraction, left-to-right adds.
#pragma clang fp contract(off)
#pragma unroll
    for (int s = 0; s < 32; s++) {
      int j = lane + (s << 6);  // 64*32 = 2048 candidates, unique per lane
      float dx = qx - pb[j * 3 + 0];
      float dy = qy - pb[j * 3 + 1];
      float dz = qz - pb[j * 3 + 2];
      float d = dx * dx;
      d = d + dy * dy;
      d = d + dz * dz;
      keys[s] = ((unsigned long long)__float_as_uint(d) << 32) | (unsigned int)j;
    }
  }
  // 2-level tournament: group mins over 8, then lane min over 4 groups.
  unsigned long long gk[4];
#pragma unroll
  for (int gi = 0; gi < 4; gi++) {
    unsigned long long m = keys[gi * 8];
#pragma unroll
    for (int s = 1; s < 8; s++) {
      unsigned long long c = keys[gi * 8 + s];
      m = (c < m) ? c : m;
    }
    gk[gi] = m;
  }
  unsigned long long lkey = gk[0];
#pragma unroll
  for (int gi = 1; gi < 4; gi++) lkey = (gk[gi] < lkey) ? gk[gi] : lkey;

  int* outp = idx_out + (size_t)wq * 32;
  for (int r = 0; r < 32; r++) {
    // wave-wide min via xor butterfly (no barriers; single wave owns the query)
    unsigned long long g = lkey;
#pragma unroll
    for (int off = 1; off < 64; off <<= 1) {
      unsigned long long o = __shfl_xor(g, off, 64);
      g = (o < g) ? o : g;
    }
    if (lkey == g) {  // unique owner lane (keys unique by index)
      outp[r] = (int)(unsigned int)g;
      // remove g from its group, rescan that group only
#pragma unroll
      for (int gi = 0; gi < 4; gi++) {
        if (gk[gi] == g) {
          unsigned long long m = ~0ULL;
#pragma unroll
          for (int s = 0; s < 8; s++) {
            unsigned long long c = keys[gi * 8 + s];
            if (c == g) { c = ~0ULL; keys[gi * 8 + s] = c; }
            m = (c < m) ? c : m;
          }
          gk[gi] = m;
        }
      }
      lkey = gk[0];
#pragma unroll
      for (int gi = 1; gi < 4; gi++) lkey = (gk[gi] < lkey) ? gk[gi] : lkey;
    }
  }
}

// ---------------------------------------------------------------------------
// fp32 tiled GEMM, 64x64 tile, K-tile 16, 256 threads, 4x4 per thread.
// MODE 0: C = A@B                      (qkv)
// MODE 1: C = gelu(A@B + bias)        (proj)
// MODE 2: C = extra + (A*av)@B + bias (head; av indexed [batch*256+k], N==256)
// ---------------------------------------------------------------------------
template <int MODE>
__global__ __launch_bounds__(256) void gemm64(const float* __restrict__ A,
                                              const float* __restrict__ Bm,
                                              const float* __restrict__ bias,
                                              const float* __restrict__ extra,
                                              const float* __restrict__ av,
                                              float* __restrict__ C,
                                              int M, int N, int K) {
  __shared__ float As[16][65];  // [k][m], +1 pad
  __shared__ float Bs[16][64];  // [k][n]
  int tid = threadIdx.x;
  int tx = tid & 15, ty = tid >> 4;
  int tileN = blockIdx.x * 64, tileM = blockIdx.y * 64;
  int arow = tid >> 2;           // 0..63
  int acol4 = (tid & 3) * 4;     // 0,4,8,12
  int brow = tid >> 4;           // 0..15
  int bcol4 = (tid & 15) * 4;
  int batch = (tileM + arow) >> 11;  // rows of a tile share the batch (64|2048)
  float acc[4][4] = {};
  for (int k0 = 0; k0 < K; k0 += 16) {
    float4 a = *(const float4*)(A + (size_t)(tileM + arow) * K + k0 + acol4);
    if (MODE == 2) {
      const float* avb = av + batch * 256 + k0 + acol4;
      a.x *= avb[0]; a.y *= avb[1]; a.z *= avb[2]; a.w *= avb[3];
    }
    float4 bv = *(const float4*)(Bm + (size_t)(k0 + brow) * N + tileN + bcol4);
    As[acol4 + 0][arow] = a.x;
    As[acol4 + 1][arow] = a.y;
    As[acol4 + 2][arow] = a.z;
    As[acol4 + 3][arow] = a.w;
    *(float4*)&Bs[brow][bcol4] = bv;
    __syncthreads();
#pragma unroll
    for (int kk = 0; kk < 16; kk++) {
      float ar[4], br[4];
#pragma unroll
      for (int i = 0; i < 4; i++) ar[i] = As[kk][ty + 16 * i];
#pragma unroll
      for (int j = 0; j < 4; j++) br[j] = Bs[kk][tx + 16 * j];
#pragma unroll
      for (int i = 0; i < 4; i++)
#pragma unroll
        for (int j = 0; j < 4; j++) acc[i][j] += ar[i] * br[j];
    }
    __syncthreads();
  }
#pragma unroll
  for (int i = 0; i < 4; i++) {
    int row = tileM + ty + 16 * i;
#pragma unroll
    for (int j = 0; j < 4; j++) {
      int col = tileN + tx + 16 * j;
      float v = acc[i][j];
      if (MODE == 1) v = gelu_f(v + bias[col]);
      else if (MODE == 2) v = extra[(size_t)row * 256 + col] + (v + bias[col]);
      C[(size_t)row * N + col] = v;
    }
  }
}

// ---------------------------------------------------------------------------
// Fused neighborhood attention, one block(128) per (b,n,group).
// rp[j][c] = gelu(rel@Wp + bp); attn_rel = per-head sum; logits = q.k*SCALE+ar;
// softmax over neighbors; out = sum a*(v+rp).
// ---------------------------------------------------------------------------
__global__ __launch_bounds__(128) void attn_kernel(
    const float* __restrict__ qkv, const float* __restrict__ pos,
    const int* __restrict__ knn,
    const float* __restrict__ Wp0, const float* __restrict__ bp0,
    const float* __restrict__ Wp1, const float* __restrict__ bp1,
    float* __restrict__ xcat) {
  const float SCALE = 0.17677669529663687f;  // 32^-0.5
  int g = blockIdx.y;
  int bn = blockIdx.x;
  int b = bn >> 11, n = bn & (NPT - 1);
  int nk = g ? 32 : 16;
  const float* Wp = g ? Wp1 : Wp0;
  const float* bp = g ? bp1 : bp0;
  int t = threadIdx.x;  // 0..127 = output channel within group
  __shared__ float q_s[128];
  __shared__ float rel_s[32][3];
  __shared__ int idx_s[32];
  __shared__ float rp[32][129];  // +1 pad: conflict-free per-head row sums
  __shared__ float logits[4][32];
  __shared__ float denom[4];
  const float* qkvb = qkv + (size_t)b * NPT * QKVW;
  q_s[t] = qkvb[(size_t)n * QKVW + g * 128 + t];
  if (t < nk) {
    int j = knn[(size_t)bn * 32 + t];
    idx_s[t] = j;
    rel_s[t][0] = pos[((size_t)b * NPT + n) * 3 + 0] - pos[((size_t)b * NPT + j) * 3 + 0];
    rel_s[t][1] = pos[((size_t)b * NPT + n) * 3 + 1] - pos[((size_t)b * NPT + j) * 3 + 1];
    rel_s[t][2] = pos[((size_t)b * NPT + n) * 3 + 2] - pos[((size_t)b * NPT + j) * 3 + 2];
  }
  __syncthreads();
  // rel-pos MLP
  float w0 = Wp[t], w1 = Wp[128 + t], w2 = Wp[256 + t], bb = bp[t];
  for (int j = 0; j < nk; j++) {
    float x = rel_s[j][0] * w0 + rel_s[j][1] * w1 + rel_s[j][2] * w2 + bb;
    rp[j][t] = gelu_f(x);
  }
  __syncthreads();
  // attn_rel + logits: thread -> (head h, neighbor j)
  {
    int h, j;
    bool active;
    if (nk == 32) { h = t >> 5; j = t & 31; active = true; }
    else          { h = t >> 4; j = t & 15; active = (t < 64); }
    if (active) {
      float ar = 0.f;
#pragma unroll
      for (int d = 0; d < 32; d++) ar += rp[j][h * 32 + d];
      const float* kr = qkvb + (size_t)idx_s[j] * QKVW + 256 + g * 128 + h * 32;
      float dot = 0.f;
#pragma unroll
      for (int d = 0; d < 32; d++) dot += q_s[h * 32 + d] * kr[d];
      logits[h][j] = dot * SCALE + ar;
    }
  }
  __syncthreads();
  // v' = rp + gathered v (in place; each thread touches only its own column)
  for (int j = 0; j < nk; j++)
    rp[j][t] += qkvb[(size_t)idx_s[j] * QKVW + 512 + g * 128 + t];
  // softmax numerator/denominator per head (4 threads, nk iters each)
  if (t < 4) {
    float mx = -3.4e38f;
    for (int j = 0; j < nk; j++) mx = fmaxf(mx, logits[t][j]);
    float s = 0.f;
    for (int j = 0; j < nk; j++) {
      float e = expf(logits[t][j] - mx);
      logits[t][j] = e;
      s += e;
    }
    denom[t] = s;
  }
  __syncthreads();
  int hh = t >> 5;
  float acc = 0.f;
  for (int j = 0; j < nk; j++) acc += logits[hh][j] * rp[j][t];
  acc /= denom[hh];
  xcat[((size_t)b * NPT + n) * DIM_ + g * 128 + t] = acc;
}

// ---------------------------------------------------------------------------
// Column partial sums of feats_proj (mean over N later). grid (B,32), 64 rows each.
// ---------------------------------------------------------------------------
__global__ __launch_bounds__(256) void colsum_kernel(const float* __restrict__ fp,
                                                     float* __restrict__ part) {
  int b = blockIdx.x, ch = blockIdx.y, t = threadIdx.x;
  const float* base = fp + ((size_t)(b * NPT + ch * 64)) * DIM_ + t;
  float s = 0.f;
  for (int r = 0; r < 64; r++) s += base[(size_t)r * DIM_];
  part[((size_t)b * 32 + ch) * DIM_ + t] = s;
}

// ---------------------------------------------------------------------------
// Tiny MSF MLP: S=mean -> Z=gelu(S@Wfc1+b) -> av=Z@Wfc2+b -> pairwise softmax.
// One block per batch, 256 threads.
// ---------------------------------------------------------------------------
__global__ __launch_bounds__(256) void msf_small_kernel(
    const float* __restrict__ part, const float* __restrict__ Wfc1,
    const float* __restrict__ bfc1, const float* __restrict__ Wfc2,
    const float* __restrict__ bfc2, float* __restrict__ av_out) {
  int b = blockIdx.x, t = threadIdx.x;
  __shared__ float S[256], Z[128], A[256];
  float s = 0.f;
  for (int ch = 0; ch < 32; ch++) s += part[((size_t)b * 32 + ch) * DIM_ + t];
  S[t] = s * (1.0f / 2048.0f);
  __syncthreads();
  if (t < 128) {
    float z = bfc1[t];
    for (int i = 0; i < 256; i++) z += S[i] * Wfc1[i * 128 + t];
    Z[t] = gelu_f(z);
  }
  __syncthreads();
  float a = bfc2[t];
  for (int j = 0; j < 128; j++) a += Z[j] * Wfc2[j * 256 + t];
  A[t] = a;
  __syncthreads();
  float pA = A[t ^ 128];  // softmax over the 2 groups, per channel
  float m = fmaxf(a, pA);
  float e = expf(a - m);
  av_out[(size_t)b * 256 + t] = e / (e + expf(pA - m));
}

// ---------------------------------------------------------------------------
extern "C" void kernel_launch(void* const* d_in, const int* in_sizes, int n_in,
                              void* d_out, int out_size, void* d_ws, size_t ws_size,
                              hipStream_t stream) {
  const float* x     = (const float*)d_in[0];
  const float* pos   = (const float*)d_in[1];
  const float* Wqkv  = (const float*)d_in[2];
  const float* Wp0   = (const float*)d_in[3];
  const float* bp0   = (const float*)d_in[4];
  const float* Wp1   = (const float*)d_in[5];
  const float* bp1   = (const float*)d_in[6];
  const float* Wproj = (const float*)d_in[7];
  const float* bproj = (const float*)d_in[8];
  const float* Wfc1  = (const float*)d_in[9];
  const float* bfc1  = (const float*)d_in[10];
  const float* Wfc2  = (const float*)d_in[11];
  const float* bfc2  = (const float*)d_in[12];
  const float* Whead = (const float*)d_in[13];
  const float* bhead = (const float*)d_in[14];
  float* out = (float*)d_out;

  // Workspace layout (bytes):
  //   [0, 1MB)            knn idx  [B*N][32] int
  //   [1MB, 1MB+25.2MB)   qkv      [B*N][768] f32  -- reused as feats_proj after attention
  //   [+, +8.4MB)         xcat     [B*N][256] f32
  //   [+, +128KB)         colsum partials [B][32][256] f32
  //   [+, +4KB)           av_sm    [B][256] f32
  char* ws = (char*)d_ws;
  size_t off = 0;
  int* idx = (int*)(ws + off);          off += (size_t)B_ * NPT * 32 * 4;      // 1 MiB
  float* qkv = (float*)(ws + off);      off += (size_t)B_ * NPT * QKVW * 4;    // 25.2 MB
  float* fp = qkv;  // reuse: qkv dead after attention
  float* xcat = (float*)(ws + off);     off += (size_t)B_ * NPT * DIM_ * 4;    // 8.4 MB
  float* part = (float*)(ws + off);     off += (size_t)B_ * 32 * DIM_ * 4;     // 128 KiB
  float* av = (float*)(ws + off);       off += (size_t)B_ * DIM_ * 4;          // 4 KiB

  const int M = B_ * NPT;  // 8192

  knn_kernel<<<M / 4, 256, 0, stream>>>(pos, idx);
  gemm64<0><<<dim3(QKVW / 64, M / 64), 256, 0, stream>>>(
      x, Wqkv, nullptr, nullptr, nullptr, qkv, M, QKVW, DIM_);
  attn_kernel<<<dim3(M, 2), 128, 0, stream>>>(qkv, pos, idx, Wp0, bp0, Wp1, bp1, xcat);
  gemm64<1><<<dim3(DIM_ / 64, M / 64), 256, 0, stream>>>(
      xcat, Wproj, bproj, nullptr, nullptr, fp, M, DIM_, DIM_);
  colsum_kernel<<<dim3(B_, 32), 256, 0, stream>>>(fp, part);
  msf_small_kernel<<<B_, 256, 0, stream>>>(part, Wfc1, bfc1, Wfc2, bfc2, av);
  gemm64<2><<<dim3(DIM_ / 64, M / 64), 256, 0, stream>>>(
      xcat, Whead, bhead, fp, av, out, M, DIM_, DIM_);
}

// Round 3
// 366.979 us; speedup vs baseline: 1.2620x; 1.1915x over previous
//
#include <hip/hip_runtime.h>
#include <cstdint>
#include <cstddef>

// Problem constants (reference: B=4, N=2048, DIM=256, heads=8, groups=2)
#define B_    4
#define NPT   2048
#define DIM_  256
#define QKVW  768   // 3*DIM

__device__ __forceinline__ float gelu_f(float x) {
  // exact gelu: x * 0.5 * (1 + erf(x/sqrt(2)))
  return 0.5f * x * (1.0f + erff(x * 0.70710678118654752440f));
}

// One DPP min-reduce step on a 64-bit key split into (hi,lo) halves.
// update_dpp with bound_ctrl=false + masks 0xf: lanes w/o valid source keep
// `old` (their own value) -> min(x,x) identity; min is idempotent so no
// row/bank masking needed. VALU pipe only — no ds_bpermute latency.
template <int CTRL>
__device__ __forceinline__ void dppmin_step(int& lo, int& hi) {
  int olo = __builtin_amdgcn_update_dpp(lo, lo, CTRL, 0xf, 0xf, false);
  int ohi = __builtin_amdgcn_update_dpp(hi, hi, CTRL, 0xf, 0xf, false);
  unsigned long long o = ((unsigned long long)(unsigned)ohi << 32) | (unsigned)olo;
  unsigned long long c = ((unsigned long long)(unsigned)hi << 32) | (unsigned)lo;
  if (o < c) { lo = olo; hi = ohi; }
}

// ---------------------------------------------------------------------------
// KNN v3: ONE WAVE per query (4 queries / 256-thread block). No barriers.
// Each lane holds 32 candidates as packed key = (dist_bits<<32)|idx (dist>=0 so
// IEEE bits are order-preserving; low-bits index = stable tie-break, matching
// numpy argsort). 2-level tournament per lane (4 group-mins of 8) so the
// extraction removal rescans only 8 keys, exec-masked to the single owner lane.
// Wave-wide min per round via 6-step DPP reduce (row_shr 1/2/4/8, bcast15/31)
// ending in lane 63, readlane -> SGPR broadcast. All VALU — the R2 version's
// shfl_xor butterfly was 384 dependent ds_bpermute ops (lgkm-latency-bound).
// ---------------------------------------------------------------------------
__global__ __launch_bounds__(256) void knn_kernel(const float* __restrict__ pos,
                                                  int* __restrict__ idx_out) {
  int wq = blockIdx.x * 4 + (threadIdx.x >> 6);  // query id 0..8191
  int lane = threadIdx.x & 63;
  int b = wq >> 11, n = wq & (NPT - 1);
  const float* pb = pos + (size_t)b * NPT * 3;
  float qx = pb[n * 3 + 0], qy = pb[n * 3 + 1], qz = pb[n * 3 + 2];

  unsigned long long keys[32];
  {
    // Match numpy rounding: no FMA contraction, left-to-right adds.
#pragma clang fp contract(off)
#pragma unroll
    for (int s = 0; s < 32; s++) {
      int j = lane + (s << 6);  // 64*32 = 2048 candidates, unique per lane
      float dx = qx - pb[j * 3 + 0];
      float dy = qy - pb[j * 3 + 1];
      float dz = qz - pb[j * 3 + 2];
      float d = dx * dx;
      d = d + dy * dy;
      d = d + dz * dz;
      keys[s] = ((unsigned long long)__float_as_uint(d) << 32) | (unsigned int)j;
    }
  }
  // 2-level tournament: group mins over 8, then lane min over 4 groups.
  unsigned long long gk[4];
#pragma unroll
  for (int gi = 0; gi < 4; gi++) {
    unsigned long long m = keys[gi * 8];
#pragma unroll
    for (int s = 1; s < 8; s++) {
      unsigned long long c = keys[gi * 8 + s];
      m = (c < m) ? c : m;
    }
    gk[gi] = m;
  }
  unsigned long long lkey = gk[0];
#pragma unroll
  for (int gi = 1; gi < 4; gi++) lkey = (gk[gi] < lkey) ? gk[gi] : lkey;

  int* outp = idx_out + (size_t)wq * 32;
  for (int r = 0; r < 32; r++) {
    // wave-wide min via DPP (VALU pipe; result accumulates into lane 63)
    int lo = (int)(unsigned)(lkey & 0xffffffffULL);
    int hi = (int)(unsigned)(lkey >> 32);
    dppmin_step<0x111>(lo, hi);  // row_shr:1
    dppmin_step<0x112>(lo, hi);  // row_shr:2
    dppmin_step<0x114>(lo, hi);  // row_shr:4
    dppmin_step<0x118>(lo, hi);  // row_shr:8
    dppmin_step<0x142>(lo, hi);  // row_bcast:15
    dppmin_step<0x143>(lo, hi);  // row_bcast:31
    unsigned int glo = (unsigned int)__builtin_amdgcn_readlane(lo, 63);
    unsigned int ghi = (unsigned int)__builtin_amdgcn_readlane(hi, 63);
    unsigned long long g = ((unsigned long long)ghi << 32) | glo;
    if (lkey == g) {  // unique owner lane (keys unique by index)
      outp[r] = (int)glo;
      // remove g from its group, rescan that group only
#pragma unroll
      for (int gi = 0; gi < 4; gi++) {
        if (gk[gi] == g) {
          unsigned long long m = ~0ULL;
#pragma unroll
          for (int s = 0; s < 8; s++) {
            unsigned long long c = keys[gi * 8 + s];
            if (c == g) { c = ~0ULL; keys[gi * 8 + s] = c; }
            m = (c < m) ? c : m;
          }
          gk[gi] = m;
        }
      }
      lkey = gk[0];
#pragma unroll
      for (int gi = 1; gi < 4; gi++) lkey = (gk[gi] < lkey) ? gk[gi] : lkey;
    }
  }
}

// ---------------------------------------------------------------------------
// fp32 tiled GEMM, 64x64 tile, K-tile 16, 256 threads, 4x4 per thread.
// MODE 0: C = A@B                      (qkv)
// MODE 1: C = gelu(A@B + bias)        (proj)
// MODE 2: C = extra + (A*av)@B + bias (head; av indexed [batch*256+k], N==256)
// ---------------------------------------------------------------------------
template <int MODE>
__global__ __launch_bounds__(256) void gemm64(const float* __restrict__ A,
                                              const float* __restrict__ Bm,
                                              const float* __restrict__ bias,
                                              const float* __restrict__ extra,
                                              const float* __restrict__ av,
                                              float* __restrict__ C,
                                              int M, int N, int K) {
  __shared__ float As[16][65];  // [k][m], +1 pad
  __shared__ float Bs[16][64];  // [k][n]
  int tid = threadIdx.x;
  int tx = tid & 15, ty = tid >> 4;
  int tileN = blockIdx.x * 64, tileM = blockIdx.y * 64;
  int arow = tid >> 2;           // 0..63
  int acol4 = (tid & 3) * 4;     // 0,4,8,12
  int brow = tid >> 4;           // 0..15
  int bcol4 = (tid & 15) * 4;
  int batch = (tileM + arow) >> 11;  // rows of a tile share the batch (64|2048)
  float acc[4][4] = {};
  for (int k0 = 0; k0 < K; k0 += 16) {
    float4 a = *(const float4*)(A + (size_t)(tileM + arow) * K + k0 + acol4);
    if (MODE == 2) {
      const float* avb = av + batch * 256 + k0 + acol4;
      a.x *= avb[0]; a.y *= avb[1]; a.z *= avb[2]; a.w *= avb[3];
    }
    float4 bv = *(const float4*)(Bm + (size_t)(k0 + brow) * N + tileN + bcol4);
    As[acol4 + 0][arow] = a.x;
    As[acol4 + 1][arow] = a.y;
    As[acol4 + 2][arow] = a.z;
    As[acol4 + 3][arow] = a.w;
    *(float4*)&Bs[brow][bcol4] = bv;
    __syncthreads();
#pragma unroll
    for (int kk = 0; kk < 16; kk++) {
      float ar[4], br[4];
#pragma unroll
      for (int i = 0; i < 4; i++) ar[i] = As[kk][ty + 16 * i];
#pragma unroll
      for (int j = 0; j < 4; j++) br[j] = Bs[kk][tx + 16 * j];
#pragma unroll
      for (int i = 0; i < 4; i++)
#pragma unroll
        for (int j = 0; j < 4; j++) acc[i][j] += ar[i] * br[j];
    }
    __syncthreads();
  }
#pragma unroll
  for (int i = 0; i < 4; i++) {
    int row = tileM + ty + 16 * i;
#pragma unroll
    for (int j = 0; j < 4; j++) {
      int col = tileN + tx + 16 * j;
      float v = acc[i][j];
      if (MODE == 1) v = gelu_f(v + bias[col]);
      else if (MODE == 2) v = extra[(size_t)row * 256 + col] + (v + bias[col]);
      C[(size_t)row * N + col] = v;
    }
  }
}

// ---------------------------------------------------------------------------
// Fused neighborhood attention, one block(128) per (b,n,group).
// rp[j][c] = gelu(rel@Wp + bp); attn_rel = per-head sum; logits = q.k*SCALE+ar;
// softmax over neighbors; out = sum a*(v+rp).
// ---------------------------------------------------------------------------
__global__ __launch_bounds__(128) void attn_kernel(
    const float* __restrict__ qkv, const float* __restrict__ pos,
    const int* __restrict__ knn,
    const float* __restrict__ Wp0, const float* __restrict__ bp0,
    const float* __restrict__ Wp1, const float* __restrict__ bp1,
    float* __restrict__ xcat) {
  const float SCALE = 0.17677669529663687f;  // 32^-0.5
  int g = blockIdx.y;
  int bn = blockIdx.x;
  int b = bn >> 11, n = bn & (NPT - 1);
  int nk = g ? 32 : 16;
  const float* Wp = g ? Wp1 : Wp0;
  const float* bp = g ? bp1 : bp0;
  int t = threadIdx.x;  // 0..127 = output channel within group
  __shared__ float q_s[128];
  __shared__ float rel_s[32][3];
  __shared__ int idx_s[32];
  __shared__ float rp[32][129];  // +1 pad: conflict-free per-head row sums
  __shared__ float logits[4][32];
  __shared__ float denom[4];
  const float* qkvb = qkv + (size_t)b * NPT * QKVW;
  q_s[t] = qkvb[(size_t)n * QKVW + g * 128 + t];
  if (t < nk) {
    int j = knn[(size_t)bn * 32 + t];
    idx_s[t] = j;
    rel_s[t][0] = pos[((size_t)b * NPT + n) * 3 + 0] - pos[((size_t)b * NPT + j) * 3 + 0];
    rel_s[t][1] = pos[((size_t)b * NPT + n) * 3 + 1] - pos[((size_t)b * NPT + j) * 3 + 1];
    rel_s[t][2] = pos[((size_t)b * NPT + n) * 3 + 2] - pos[((size_t)b * NPT + j) * 3 + 2];
  }
  __syncthreads();
  // rel-pos MLP
  float w0 = Wp[t], w1 = Wp[128 + t], w2 = Wp[256 + t], bb = bp[t];
  for (int j = 0; j < nk; j++) {
    float x = rel_s[j][0] * w0 + rel_s[j][1] * w1 + rel_s[j][2] * w2 + bb;
    rp[j][t] = gelu_f(x);
  }
  __syncthreads();
  // attn_rel + logits: thread -> (head h, neighbor j)
  {
    int h, j;
    bool active;
    if (nk == 32) { h = t >> 5; j = t & 31; active = true; }
    else          { h = t >> 4; j = t & 15; active = (t < 64); }
    if (active) {
      float ar = 0.f;
#pragma unroll
      for (int d = 0; d < 32; d++) ar += rp[j][h * 32 + d];
      const float* kr = qkvb + (size_t)idx_s[j] * QKVW + 256 + g * 128 + h * 32;
      float dot = 0.f;
#pragma unroll
      for (int d = 0; d < 32; d++) dot += q_s[h * 32 + d] * kr[d];
      logits[h][j] = dot * SCALE + ar;
    }
  }
  __syncthreads();
  // v' = rp + gathered v (in place; each thread touches only its own column)
  for (int j = 0; j < nk; j++)
    rp[j][t] += qkvb[(size_t)idx_s[j] * QKVW + 512 + g * 128 + t];
  // softmax numerator/denominator per head (4 threads, nk iters each)
  if (t < 4) {
    float mx = -3.4e38f;
    for (int j = 0; j < nk; j++) mx = fmaxf(mx, logits[t][j]);
    float s = 0.f;
    for (int j = 0; j < nk; j++) {
      float e = expf(logits[t][j] - mx);
      logits[t][j] = e;
      s += e;
    }
    denom[t] = s;
  }
  __syncthreads();
  int hh = t >> 5;
  float acc = 0.f;
  for (int j = 0; j < nk; j++) acc += logits[hh][j] * rp[j][t];
  acc /= denom[hh];
  xcat[((size_t)b * NPT + n) * DIM_ + g * 128 + t] = acc;
}

// ---------------------------------------------------------------------------
// Column partial sums of feats_proj (mean over N later). grid (B,32), 64 rows each.
// ---------------------------------------------------------------------------
__global__ __launch_bounds__(256) void colsum_kernel(const float* __restrict__ fp,
                                                     float* __restrict__ part) {
  int b = blockIdx.x, ch = blockIdx.y, t = threadIdx.x;
  const float* base = fp + ((size_t)(b * NPT + ch * 64)) * DIM_ + t;
  float s = 0.f;
  for (int r = 0; r < 64; r++) s += base[(size_t)r * DIM_];
  part[((size_t)b * 32 + ch) * DIM_ + t] = s;
}

// ---------------------------------------------------------------------------
// Tiny MSF MLP: S=mean -> Z=gelu(S@Wfc1+b) -> av=Z@Wfc2+b -> pairwise softmax.
// One block per batch, 256 threads.
// ---------------------------------------------------------------------------
__global__ __launch_bounds__(256) void msf_small_kernel(
    const float* __restrict__ part, const float* __restrict__ Wfc1,
    const float* __restrict__ bfc1, const float* __restrict__ Wfc2,
    const float* __restrict__ bfc2, float* __restrict__ av_out) {
  int b = blockIdx.x, t = threadIdx.x;
  __shared__ float S[256], Z[128], A[256];
  float s = 0.f;
  for (int ch = 0; ch < 32; ch++) s += part[((size_t)b * 32 + ch) * DIM_ + t];
  S[t] = s * (1.0f / 2048.0f);
  __syncthreads();
  if (t < 128) {
    float z = bfc1[t];
    for (int i = 0; i < 256; i++) z += S[i] * Wfc1[i * 128 + t];
    Z[t] = gelu_f(z);
  }
  __syncthreads();
  float a = bfc2[t];
  for (int j = 0; j < 128; j++) a += Z[j] * Wfc2[j * 256 + t];
  A[t] = a;
  __syncthreads();
  float pA = A[t ^ 128];  // softmax over the 2 groups, per channel
  float m = fmaxf(a, pA);
  float e = expf(a - m);
  av_out[(size_t)b * 256 + t] = e / (e + expf(pA - m));
}

// ---------------------------------------------------------------------------
extern "C" void kernel_launch(void* const* d_in, const int* in_sizes, int n_in,
                              void* d_out, int out_size, void* d_ws, size_t ws_size,
                              hipStream_t stream) {
  const float* x     = (const float*)d_in[0];
  const float* pos   = (const float*)d_in[1];
  const float* Wqkv  = (const float*)d_in[2];
  const float* Wp0   = (const float*)d_in[3];
  const float* bp0   = (const float*)d_in[4];
  const float* Wp1   = (const float*)d_in[5];
  const float* bp1   = (const float*)d_in[6];
  const float* Wproj = (const float*)d_in[7];
  const float* bproj = (const float*)d_in[8];
  const float* Wfc1  = (const float*)d_in[9];
  const float* bfc1  = (const float*)d_in[10];
  const float* Wfc2  = (const float*)d_in[11];
  const float* bfc2  = (const float*)d_in[12];
  const float* Whead = (const float*)d_in[13];
  const float* bhead = (const float*)d_in[14];
  float* out = (float*)d_out;

  // Workspace layout (bytes):
  //   [0, 1MB)            knn idx  [B*N][32] int
  //   [1MB, 1MB+25.2MB)   qkv      [B*N][768] f32  -- reused as feats_proj after attention
  //   [+, +8.4MB)         xcat     [B*N][256] f32
  //   [+, +128KB)         colsum partials [B][32][256] f32
  //   [+, +4KB)           av_sm    [B][256] f32
  char* ws = (char*)d_ws;
  size_t off = 0;
  int* idx = (int*)(ws + off);          off += (size_t)B_ * NPT * 32 * 4;      // 1 MiB
  float* qkv = (float*)(ws + off);      off += (size_t)B_ * NPT * QKVW * 4;    // 25.2 MB
  float* fp = qkv;  // reuse: qkv dead after attention
  float* xcat = (float*)(ws + off);     off += (size_t)B_ * NPT * DIM_ * 4;    // 8.4 MB
  float* part = (float*)(ws + off);     off += (size_t)B_ * 32 * DIM_ * 4;     // 128 KiB
  float* av = (float*)(ws + off);       off += (size_t)B_ * DIM_ * 4;          // 4 KiB

  const int M = B_ * NPT;  // 8192

  knn_kernel<<<M / 4, 256, 0, stream>>>(pos, idx);
  gemm64<0><<<dim3(QKVW / 64, M / 64), 256, 0, stream>>>(
      x, Wqkv, nullptr, nullptr, nullptr, qkv, M, QKVW, DIM_);
  attn_kernel<<<dim3(M, 2), 128, 0, stream>>>(qkv, pos, idx, Wp0, bp0, Wp1, bp1, xcat);
  gemm64<1><<<dim3(DIM_ / 64, M / 64), 256, 0, stream>>>(
      xcat, Wproj, bproj, nullptr, nullptr, fp, M, DIM_, DIM_);
  colsum_kernel<<<dim3(B_, 32), 256, 0, stream>>>(fp, part);
  msf_small_kernel<<<B_, 256, 0, stream>>>(part, Wfc1, bfc1, Wfc2, bfc2, av);
  gemm64<2><<<dim3(DIM_ / 64, M / 64), 256, 0, stream>>>(
      xcat, Whead, bhead, fp, av, out, M, DIM_, DIM_);
}